// Round 2
// baseline (824.013 us; speedup 1.0000x reference)
//
#include <hip/hip_runtime.h>

#define B_TOTAL 16384
#define INPUT   512
#define HID     128
#define OUTW    64
#define STEPS   10
#define GATES   512   // 4*HID

// ws layout (floats):
//   W_effP [128][128][4]  off 0       ((W_hh + W_ih@W_out), packed [k][h][gate])
//   W_hhP  [128][128][4]  off 65536   (W_hh packed [k][h][gate], for t=0)
//   W_initP[128][128][4]  off 131072  (W_init packed [k0/4][h][k&3])
//   W_outP [32][64][4]    off 196608  (W_out packed [k0/4][jo][k&3])
//   b_all  [512]          off 204800  (b_ih+b_hh+W_ih@b_out)
//   b2     [512]          off 205312  (b_ih+b_hh, for t=0 where o=0)
// total 205824 floats = 823 KB

__global__ __launch_bounds__(128) void precompute_kernel(
    const float* __restrict__ W_ih, const float* __restrict__ W_hh,
    const float* __restrict__ b_ih, const float* __restrict__ b_hh,
    const float* __restrict__ W_init, const float* __restrict__ W_out,
    const float* __restrict__ b_out, float* __restrict__ ws)
{
    const int j = blockIdx.x;   // 0..511: gate row (also reused as input-col for W_init)
    const int k = threadIdx.x;  // 0..127: hidden index
    float* W_effP  = ws;
    float* W_hhP   = ws + 65536;
    float* W_initP = ws + 131072;
    float* W_outP  = ws + 196608;
    float* b_all   = ws + 204800;
    float* b2      = ws + 205312;

    const int g  = j >> 7;    // gate 0..3 (i,f,g,o)
    const int jj = j & 127;   // hidden col within gate

    float whh = W_hh[j*HID + k];
    float acc = whh;
    for (int m = 0; m < OUTW; ++m)
        acc += W_ih[j*OUTW + m] * W_out[m*HID + k];
    W_effP[(k*HID + jj)*4 + g] = acc;     // [k][jj][g]
    W_hhP [(k*HID + jj)*4 + g] = whh;
    // W_init: j = input col (0..511), k = hidden h
    W_initP[((j>>2)*HID + k)*4 + (j&3)] = W_init[k*INPUT + j];
    if (j < OUTW) W_outP[((k>>2)*OUTW + j)*4 + (k&3)] = W_out[j*HID + k];
    if (k == 0) {
        float s = 0.f;
        for (int m = 0; m < OUTW; ++m) s += W_ih[j*OUTW + m] * b_out[m];
        float bb = b_ih[j] + b_hh[j];
        b_all[j] = bb + s;
        b2[j]    = bb;
    }
}

__device__ __forceinline__ float fast_sigmoid(float x) {
    return 1.f / (1.f + __builtin_amdgcn_exp2f(-1.4426950408889634f * x));
}
__device__ __forceinline__ float fast_tanh(float x) {
    return 1.f - 2.f / (1.f + __builtin_amdgcn_exp2f(2.8853900817779268f * x));
}

#define RPB 32    // rows per block
#define TPB 512

__global__ __launch_bounds__(TPB, 4) void lstm_kernel(
    const float* __restrict__ x, const float* __restrict__ ws,
    const float* __restrict__ b_init, const float* __restrict__ b_out,
    float* __restrict__ out)
{
    __shared__ float hxs[RPB][HID];    // 16 KB only

    const float4* W_effP4  = (const float4*)(ws);
    const float4* W_hhP4   = (const float4*)(ws + 65536);
    const float4* W_initP4 = (const float4*)(ws + 131072);
    const float4* W_outP4  = (const float4*)(ws + 196608);
    const float*  b_all    = ws + 204800;
    const float*  b2       = ws + 205312;

    const int tid = threadIdx.x;
    const int h   = tid & 127;     // owned hidden index
    const int rq  = tid >> 7;      // 0..3 -> row block of 8
    const int b0  = blockIdx.x * RPB;

    // ---- init GEMM: hx0[r][h] = b_init[h] + sum_k x[r][k]*W_init[h][k] ----
    // x read directly from global: per-wave uniform row address -> broadcast loads.
    float cx[8];
    {
        float acc[8];
        const float binit = b_init[h];
        #pragma unroll
        for (int r = 0; r < 8; ++r) acc[r] = binit;
        for (int k0 = 0; k0 < INPUT; k0 += 4) {
            float4 wv = W_initP4[(k0>>2)*HID + h];   // W_init[h][k0..k0+3]
            #pragma unroll
            for (int r = 0; r < 8; ++r) {
                float4 xv = *(const float4*)&x[(size_t)(b0 + rq*8 + r)*INPUT + k0];
                acc[r] = fmaf(xv.x, wv.x, acc[r]);
                acc[r] = fmaf(xv.y, wv.y, acc[r]);
                acc[r] = fmaf(xv.z, wv.z, acc[r]);
                acc[r] = fmaf(xv.w, wv.w, acc[r]);
            }
        }
        #pragma unroll
        for (int r = 0; r < 8; ++r) { cx[r] = acc[r]; hxs[rq*8 + r][h] = acc[r]; }
    }
    __syncthreads();

    const int jo = tid & 63;   // out-GEMM column
    const int ro = tid >> 6;   // 0..7 -> rows {ro, 8+ro, 16+ro, 24+ro}
    const float boutj = b_out[jo];

    for (int t = 0; t < STEPS; ++t) {
        const float4* W4 = (t == 0) ? W_hhP4 : W_effP4;
        const float*  bb = (t == 0) ? b2    : b_all;

        float aI[8], aF[8], aG[8], aO[8];
        {
            const float bIv = bb[h], bFv = bb[128+h], bGv = bb[256+h], bOv = bb[384+h];
            #pragma unroll
            for (int r = 0; r < 8; ++r) { aI[r]=bIv; aF[r]=bFv; aG[r]=bGv; aO[r]=bOv; }
        }
        for (int k0 = 0; k0 < HID; k0 += 4) {
            // one dwordx4 per k: all 4 gate weights for (k, h)
            float4 w0 = W4[(k0+0)*HID + h];
            float4 w1 = W4[(k0+1)*HID + h];
            float4 w2 = W4[(k0+2)*HID + h];
            float4 w3 = W4[(k0+3)*HID + h];
            #pragma unroll
            for (int r = 0; r < 8; ++r) {
                float4 hv = *(const float4*)&hxs[rq*8 + r][k0];
                aI[r] = fmaf(hv.x, w0.x, aI[r]); aF[r] = fmaf(hv.x, w0.y, aF[r]);
                aG[r] = fmaf(hv.x, w0.z, aG[r]); aO[r] = fmaf(hv.x, w0.w, aO[r]);
                aI[r] = fmaf(hv.y, w1.x, aI[r]); aF[r] = fmaf(hv.y, w1.y, aF[r]);
                aG[r] = fmaf(hv.y, w1.z, aG[r]); aO[r] = fmaf(hv.y, w1.w, aO[r]);
                aI[r] = fmaf(hv.z, w2.x, aI[r]); aF[r] = fmaf(hv.z, w2.y, aF[r]);
                aG[r] = fmaf(hv.z, w2.z, aG[r]); aO[r] = fmaf(hv.z, w2.w, aO[r]);
                aI[r] = fmaf(hv.w, w3.x, aI[r]); aF[r] = fmaf(hv.w, w3.y, aF[r]);
                aG[r] = fmaf(hv.w, w3.z, aG[r]); aO[r] = fmaf(hv.w, w3.w, aO[r]);
            }
        }
        __syncthreads();   // all reads of old hxs complete

        #pragma unroll
        for (int r = 0; r < 8; ++r) {
            float ig = fast_sigmoid(aI[r]);
            float fg = fast_sigmoid(aF[r]);
            float gg = fast_tanh(aG[r]);
            float og = fast_sigmoid(aO[r]);
            float c  = fmaf(fg, cx[r], ig * gg);
            cx[r] = c;
            hxs[rq*8 + r][h] = og * fast_tanh(c);
        }
        __syncthreads();   // new hxs visible

        // ---- out GEMM: o_t[row][jo] = b_out[jo] + sum_k hx[row][k]*W_out[jo][k] ----
        float oacc[4];
        #pragma unroll
        for (int rr = 0; rr < 4; ++rr) oacc[rr] = boutj;
        for (int k0 = 0; k0 < HID; k0 += 4) {
            float4 wv = W_outP4[(k0>>2)*OUTW + jo];   // W_out[jo][k0..k0+3]
            #pragma unroll
            for (int rr = 0; rr < 4; ++rr) {
                float4 hv = *(const float4*)&hxs[rr*8 + ro][k0];
                oacc[rr] = fmaf(hv.x, wv.x, oacc[rr]);
                oacc[rr] = fmaf(hv.y, wv.y, oacc[rr]);
                oacc[rr] = fmaf(hv.z, wv.z, oacc[rr]);
                oacc[rr] = fmaf(hv.w, wv.w, oacc[rr]);
            }
        }
        #pragma unroll
        for (int rr = 0; rr < 4; ++rr) {
            int row = rr*8 + ro;
            // non-temporal: streaming writes must not evict L2-resident weights
            __builtin_nontemporal_store(oacc[rr],
                &out[(size_t)(b0 + row)*(STEPS*OUTW) + t*OUTW + jo]);
        }
        // no barrier needed: next iteration only READS hxs until its own post-gates barrier
    }
}

extern "C" void kernel_launch(void* const* d_in, const int* in_sizes, int n_in,
                              void* d_out, int out_size, void* d_ws, size_t ws_size,
                              hipStream_t stream)
{
    const float* x      = (const float*)d_in[0];
    const float* W_ih   = (const float*)d_in[1];
    const float* W_hh   = (const float*)d_in[2];
    const float* b_ih   = (const float*)d_in[3];
    const float* b_hh   = (const float*)d_in[4];
    const float* W_init = (const float*)d_in[5];
    const float* b_init = (const float*)d_in[6];
    const float* W_out  = (const float*)d_in[7];
    const float* b_out  = (const float*)d_in[8];
    float* out = (float*)d_out;
    float* ws  = (float*)d_ws;

    precompute_kernel<<<GATES, HID, 0, stream>>>(W_ih, W_hh, b_ih, b_hh, W_init, W_out, b_out, ws);
    lstm_kernel<<<B_TOTAL/RPB, TPB, 0, stream>>>(x, ws, b_init, b_out, out);
}